// Round 3
// baseline (5365.723 us; speedup 1.0000x reference)
//
#include <hip/hip_runtime.h>
#include <hip/hip_fp16.h>

#define TT 8
#define NN 50000
#define EE 800000
#define HH 128
#define LL 2

typedef __attribute__((ext_vector_type(8))) short short8_t;
typedef __attribute__((ext_vector_type(4))) float f32x4;

__device__ __forceinline__ float bf2f(unsigned short b){ return __uint_as_float(((unsigned)b)<<16); }
__device__ __forceinline__ unsigned short f2bf(float f){
  unsigned u = __float_as_uint(f);
  u += 0x7fffu + ((u>>16)&1u);
  return (unsigned short)(u>>16);
}
__device__ __forceinline__ float fin(float v){
  return (v == v && fabsf(v) < 1e30f) ? v : 0.0f;   // NaN/Inf -> 0
}
__device__ __forceinline__ float sigm(float x){ return 1.0f/(1.0f+__expf(-x)); }
__device__ __forceinline__ float tanh_fast(float x){
  float t = __expf(-2.0f*fabsf(x));
  float r = (1.0f-t)/(1.0f+t);
  return copysignf(r,x);
}

// ---------------- dtype detection ----------------
// flag=0: tensors are bf16. flag=1: tensors are f32.
__global__ void k_detect(const unsigned short* __restrict__ xr, int* __restrict__ flag){
  __shared__ int sm[256];
  int bad = 0;
  for (int i = threadIdx.x; i < 4096; i += 256){
    float v = bf2f(xr[i]);
    if (!(fabsf(v) < 64.0f)) bad++;       // NaN compares false -> counted
  }
  sm[threadIdx.x] = bad; __syncthreads();
  for (int off=128; off>0; off>>=1){
    if (threadIdx.x < off) sm[threadIdx.x] += sm[threadIdx.x+off];
    __syncthreads();
  }
  if (threadIdx.x == 0) flag[0] = (sm[0] > 8) ? 1 : 0;
}

// ---------------- CSR build ----------------
__global__ void k_hist(const int* __restrict__ row, int* __restrict__ counts, int E){
  int e = blockIdx.x*256 + threadIdx.x;
  if (e < E){
    int r = row[e];
    if ((unsigned)r < (unsigned)NN) atomicAdd(&counts[r], 1);
  }
}
__global__ void k_dinv(const int* __restrict__ counts, float* __restrict__ dinv, int N){
  int i = blockIdx.x*256 + threadIdx.x;
  if (i < N) dinv[i] = rsqrtf((float)counts[i] + 2.0f);
}
__global__ void k_reduce(const int* __restrict__ counts, int* __restrict__ part, int N){
  __shared__ int sm[256];
  int i = blockIdx.x*256 + threadIdx.x;
  sm[threadIdx.x] = (i < N) ? counts[i] : 0;
  __syncthreads();
  for (int off=128; off>0; off>>=1){
    if (threadIdx.x < off) sm[threadIdx.x] += sm[threadIdx.x+off];
    __syncthreads();
  }
  if (threadIdx.x == 0) part[blockIdx.x] = sm[0];
}
__global__ void k_scan_partials(const int* __restrict__ part, int* __restrict__ pscan,
                                int nb, int* __restrict__ rowptr, int N, int E){
  __shared__ int sm[256];
  int t = threadIdx.x;
  int v = (t < nb) ? part[t] : 0;
  sm[t] = v; __syncthreads();
  for (int off=1; off<256; off<<=1){
    int x = (t >= off) ? sm[t-off] : 0;
    __syncthreads();
    sm[t] += x;
    __syncthreads();
  }
  if (t < nb) pscan[t] = sm[t] - v;   // exclusive
  if (t == 0) rowptr[N] = E;
}
__global__ void k_scan_final(const int* __restrict__ counts, const int* __restrict__ pscan,
                             int* __restrict__ rowptr, int* __restrict__ cursor, int N){
  __shared__ int sm[256];
  int t = threadIdx.x;
  int i = blockIdx.x*256 + t;
  int v = (i < N) ? counts[i] : 0;
  sm[t] = v; __syncthreads();
  for (int off=1; off<256; off<<=1){
    int x = (t >= off) ? sm[t-off] : 0;
    __syncthreads();
    sm[t] += x;
    __syncthreads();
  }
  int ex = sm[t] - v + pscan[blockIdx.x];
  if (i < N){ rowptr[i] = ex; cursor[i] = ex; }
}
__global__ void k_fill(const int* __restrict__ row, const int* __restrict__ col,
                       int* __restrict__ cursor, const float* __restrict__ dinv,
                       int* __restrict__ colss, float* __restrict__ wsrc, int E){
  int e = blockIdx.x*256 + threadIdx.x;
  if (e < E){
    int r = row[e];
    if ((unsigned)r >= (unsigned)NN) return;
    int p = atomicAdd(&cursor[r], 1);
    if ((unsigned)p >= (unsigned)EE) return;
    int c = col[e];
    if ((unsigned)c >= (unsigned)NN) c = 0;
    colss[p] = c;
    wsrc[p] = dinv[c];
  }
}
__global__ void k_h0(const void* __restrict__ h0, float* __restrict__ h,
                     const int* __restrict__ flag, int n){
  const int fl = *flag;
  int i = blockIdx.x*256 + threadIdx.x;
  if (i < n){
    float v = fl ? ((const float*)h0)[i] : bf2f(((const unsigned short*)h0)[i]);
    h[i] = fin(v);
  }
}
// Wt_hi/Wt_lo: [12][128n][128k] bf16, hi/lo split of W^T
__global__ void k_transpose(const void* W0, const void* W1, const void* W2,
                            const void* W3, const void* W4, const void* W5,
                            unsigned short* __restrict__ Wt_hi,
                            unsigned short* __restrict__ Wt_lo,
                            const int* __restrict__ flag){
  const int fl = *flag;
  int mat = blockIdx.y;            // w*2 + l
  int wsel = mat >> 1, l = mat & 1;
  const void* W;
  switch (wsel){
    case 0: W = W0; break; case 1: W = W1; break; case 2: W = W2; break;
    case 3: W = W3; break; case 4: W = W4; break; default: W = W5; break;
  }
  int idx = blockIdx.x*256 + threadIdx.x;   // n*128 + k
  int n = idx >> 7, k = idx & 127;
  size_t src = (size_t)l*16384 + (size_t)k*128 + n;
  float v = fl ? ((const float*)W)[src] : bf2f(((const unsigned short*)W)[src]);
  v = fin(v);
  unsigned short hi = f2bf(v);
  unsigned short lo = f2bf(v - bf2f(hi));
  Wt_hi[(size_t)mat*16384 + idx] = hi;
  Wt_lo[(size_t)mat*16384 + idx] = lo;
}

// ---------------- dual-source split-bf16 GEMM (128-wide output) ----------------
// C[M,128] = split(S1)@(WXh+WXl) + split(S2)@(WHh+WHl)
// S1: x (bf16 if flag=0, f32 if flag=1; +s1_off elements) or h (f32, s1_is_x=0)
// S2: f32 (s2_fp16=0) or fp16 (s2_fp16=1)
__global__ __launch_bounds__(256) void gemm_one(
    const void* __restrict__ S1, long s1_off, int s1_is_x,
    const void* __restrict__ S2, int s2_fp16,
    const unsigned short* __restrict__ WXh, const unsigned short* __restrict__ WHh,
    const unsigned short* __restrict__ WXl, const unsigned short* __restrict__ WHl,
    float* __restrict__ C, int M, const int* __restrict__ flag)
{
  __shared__ short Alds[128*72];
  __shared__ short Blds[128*72];
  const int fl = *flag;
  const int s1bf = s1_is_x && !fl;          // S1 readable as exact bf16
  const int nit = fl ? 16 : 8;              // with f32 weights, also apply lo planes
  const int tid = threadIdx.x;
  const int m0 = blockIdx.x * 128;

  const int lane = tid & 63;
  const int wid  = tid >> 6;
  const int wm = (wid & 1) << 6;
  const int wn = (wid >> 1) << 6;
  const int lrow = lane & 15;
  const int lk   = (lane >> 4) << 3;

  f32x4 acc[4][4];
#pragma unroll
  for (int i=0;i<4;++i)
#pragma unroll
    for (int j=0;j<4;++j) acc[i][j] = f32x4{0.f,0.f,0.f,0.f};

  const int mrow = tid >> 1;   // 0..127 (A row / B row)
  const int half = tid & 1;
  int arow_g = m0 + mrow; if (arow_g >= M) arow_g = M-1;

  for (int it=0; it<nit; ++it){
    const int phase = it >> 2;              // 0:(S1,WXh) 1:(S2,WHh) 2:(S1,WXl) 3:(S2,WHl)
    const int k0 = (it & 3) * 32;
    const int koff = k0 + half*16;          // source-column offset, 16 per thread
    const bool useS1 = (phase & 1) == 0;
    // ---- stage A: 16 source values -> 32 bf16 (hi/lo interleave) ----
    {
      unsigned pk[16];
      if (useS1 && s1bf){
        const unsigned short* sp = (const unsigned short*)S1 + s1_off + (size_t)arow_g*HH + koff;
        __align__(16) unsigned short tmp[16];
        *(uint4*)&tmp[0] = ((const uint4*)sp)[0];
        *(uint4*)&tmp[8] = ((const uint4*)sp)[1];
#pragma unroll
        for (int j=0;j<16;++j){
          unsigned short t = tmp[j];
          if ((t & 0x7F80u) == 0x7F80u) t = 0;   // sanitize NaN/Inf bf16
          pk[j] = (unsigned)t;                   // lo = 0
        }
      } else {
        __align__(16) float f[16];
        if (useS1){
          const float* sp = (const float*)S1 + s1_off + (size_t)arow_g*HH + koff;
          *(float4*)&f[0]  = ((const float4*)sp)[0];
          *(float4*)&f[4]  = ((const float4*)sp)[1];
          *(float4*)&f[8]  = ((const float4*)sp)[2];
          *(float4*)&f[12] = ((const float4*)sp)[3];
        } else if (s2_fp16){
          const __half* sp = (const __half*)S2 + (size_t)arow_g*HH + koff;
          __align__(16) __half tmp[16];
          *(uint4*)&tmp[0] = ((const uint4*)sp)[0];
          *(uint4*)&tmp[8] = ((const uint4*)sp)[1];
#pragma unroll
          for (int j=0;j<16;++j) f[j] = __half2float(tmp[j]);
        } else {
          const float* sp = (const float*)S2 + (size_t)arow_g*HH + koff;
          *(float4*)&f[0]  = ((const float4*)sp)[0];
          *(float4*)&f[4]  = ((const float4*)sp)[1];
          *(float4*)&f[8]  = ((const float4*)sp)[2];
          *(float4*)&f[12] = ((const float4*)sp)[3];
        }
#pragma unroll
        for (int j=0;j<16;++j){
          float v = fin(f[j]);
          unsigned short hi = f2bf(v);
          unsigned short lo = f2bf(v - bf2f(hi));
          pk[j] = (unsigned)hi | ((unsigned)lo << 16);
        }
      }
      short* ar = &Alds[mrow*72 + half*32];
#pragma unroll
      for (int q=0;q<4;++q){
        uint4 v; v.x=pk[q*4+0]; v.y=pk[q*4+1]; v.z=pk[q*4+2]; v.w=pk[q*4+3];
        *(uint4*)(void*)(ar + q*8) = v;
      }
    }
    // ---- stage B: 16 weight bf16 -> duplicated pairs ----
    {
      const unsigned short* wb = (phase==0) ? WXh : (phase==1) ? WHh : (phase==2) ? WXl : WHl;
      const unsigned short* wp = wb + (size_t)mrow*HH + koff;
      __align__(16) unsigned short tb[16];
      *(uint4*)&tb[0] = ((const uint4*)wp)[0];
      *(uint4*)&tb[8] = ((const uint4*)wp)[1];
      unsigned pb[16];
#pragma unroll
      for (int j=0;j<16;++j) pb[j] = ((unsigned)tb[j]) * 0x00010001u;
      short* br = &Blds[mrow*72 + half*32];
#pragma unroll
      for (int q=0;q<4;++q){
        uint4 v; v.x=pb[q*4+0]; v.y=pb[q*4+1]; v.z=pb[q*4+2]; v.w=pb[q*4+3];
        *(uint4*)(void*)(br + q*8) = v;
      }
    }
    __syncthreads();
#pragma unroll
    for (int ks=0; ks<2; ++ks){
      short8_t af[4], bfr[4];
#pragma unroll
      for (int mt=0;mt<4;++mt)
        af[mt] = *(const short8_t*)&Alds[(wm + mt*16 + lrow)*72 + ks*32 + lk];
#pragma unroll
      for (int nt=0;nt<4;++nt)
        bfr[nt] = *(const short8_t*)&Blds[(wn + nt*16 + lrow)*72 + ks*32 + lk];
#pragma unroll
      for (int mt=0;mt<4;++mt)
#pragma unroll
        for (int nt=0;nt<4;++nt)
          acc[mt][nt] = __builtin_amdgcn_mfma_f32_16x16x32_bf16(af[mt], bfr[nt], acc[mt][nt], 0, 0, 0);
    }
    __syncthreads();
  }
#pragma unroll
  for (int mt=0;mt<4;++mt){
    int rbase = m0 + wm + mt*16 + ((lane>>4)<<2);
#pragma unroll
    for (int nt=0;nt<4;++nt){
      int cc = wn + nt*16 + (lane & 15);
      f32x4 a = acc[mt][nt];
#pragma unroll
      for (int r=0;r<4;++r){
        int row = rbase + r;
        if (row < M) C[(size_t)row*HH + cc] = a[r];
      }
    }
  }
}

// ---------------- propagation (one wave per dst node) ----------------
__global__ __launch_bounds__(256) void prop_sig(
    const float* __restrict__ U, const int* __restrict__ rowptr,
    const int* __restrict__ cols, const float* __restrict__ wsrc,
    const float* __restrict__ dinv,
    const void* __restrict__ bx, const void* __restrict__ bh, int boff,
    const float* __restrict__ hl, __half2* __restrict__ outv, int mode,
    const int* __restrict__ flag, int N)
{
  const int fl = *flag;
  int lane = threadIdx.x & 63;
  int d = (blockIdx.x << 2) + (threadIdx.x >> 6);
  if (d >= N) return;
  float di = dinv[d];
  const float2* U2 = (const float2*)U;    // row = 64 float2
  float2 a = U2[(size_t)d*64 + lane];
  float sw = 2.0f*di;
  a.x *= sw; a.y *= sw;
  int b = rowptr[d], e = rowptr[d+1];
  if (b < 0) b = 0; if (e > EE) e = EE; if (e < b) e = b;
  for (int base=b; base<e; base+=64){
    int cnt = e - base; if (cnt > 64) cnt = 64;
    int idx = base + lane;
    int mc = (idx < e) ? cols[idx] : 0;
    float mw = (idx < e) ? wsrc[idx] : 0.0f;
    if ((unsigned)mc >= (unsigned)NN){ mc = 0; mw = 0.0f; }
    for (int j=0;j<cnt;++j){
      int s = __shfl(mc, j);
      float w = __shfl(mw, j);
      float2 v = U2[(size_t)s*64 + lane];
      a.x += w*v.x; a.y += w*v.y;
    }
  }
  int c = boff + (lane << 1);
  float bx0 = fl ? ((const float*)bx)[c]   : bf2f(((const unsigned short*)bx)[c]);
  float bx1 = fl ? ((const float*)bx)[c+1] : bf2f(((const unsigned short*)bx)[c+1]);
  float bh0 = fl ? ((const float*)bh)[c]   : bf2f(((const unsigned short*)bh)[c]);
  float bh1 = fl ? ((const float*)bh)[c+1] : bf2f(((const unsigned short*)bh)[c+1]);
  float g0 = sigm(di*a.x + fin(bx0) + fin(bh0));
  float g1 = sigm(di*a.y + fin(bx1) + fin(bh1));
  if (mode == 1){
    float2 hv = ((const float2*)hl)[(size_t)d*64 + lane];
    g0 *= hv.x; g1 *= hv.y;
  }
  __half2 o; o.x = __float2half_rn(g0); o.y = __float2half_rn(g1);
  outv[(size_t)d*64 + lane] = o;
}

__global__ __launch_bounds__(256) void prop_h(
    const float* __restrict__ U, const int* __restrict__ rowptr,
    const int* __restrict__ cols, const float* __restrict__ wsrc,
    const float* __restrict__ dinv,
    const void* __restrict__ bx, const void* __restrict__ bh, int boff,
    const __half2* __restrict__ zbuf, float* __restrict__ hl,
    void* __restrict__ outbase, long out_off, int has_out,
    const int* __restrict__ flag, int N)
{
  const int fl = *flag;
  int lane = threadIdx.x & 63;
  int d = (blockIdx.x << 2) + (threadIdx.x >> 6);
  if (d >= N) return;
  float di = dinv[d];
  const float2* U2 = (const float2*)U;
  float2 a = U2[(size_t)d*64 + lane];
  float sw = 2.0f*di;
  a.x *= sw; a.y *= sw;
  int b = rowptr[d], e = rowptr[d+1];
  if (b < 0) b = 0; if (e > EE) e = EE; if (e < b) e = b;
  for (int base=b; base<e; base+=64){
    int cnt = e - base; if (cnt > 64) cnt = 64;
    int idx = base + lane;
    int mc = (idx < e) ? cols[idx] : 0;
    float mw = (idx < e) ? wsrc[idx] : 0.0f;
    if ((unsigned)mc >= (unsigned)NN){ mc = 0; mw = 0.0f; }
    for (int j=0;j<cnt;++j){
      int s = __shfl(mc, j);
      float w = __shfl(mw, j);
      float2 v = U2[(size_t)s*64 + lane];
      a.x += w*v.x; a.y += w*v.y;
    }
  }
  int c = boff + (lane << 1);
  float bx0 = fl ? ((const float*)bx)[c]   : bf2f(((const unsigned short*)bx)[c]);
  float bx1 = fl ? ((const float*)bx)[c+1] : bf2f(((const unsigned short*)bx)[c+1]);
  float bh0 = fl ? ((const float*)bh)[c]   : bf2f(((const unsigned short*)bh)[c]);
  float bh1 = fl ? ((const float*)bh)[c+1] : bf2f(((const unsigned short*)bh)[c+1]);
  float ht0 = tanh_fast(di*a.x + fin(bx0) + fin(bh0));
  float ht1 = tanh_fast(di*a.y + fin(bx1) + fin(bh1));
  __half2 zv2 = zbuf[(size_t)d*64 + lane];
  float z0 = __half2float(zv2.x), z1 = __half2float(zv2.y);
  float2 hv = ((const float2*)hl)[(size_t)d*64 + lane];
  float hn0 = z0*hv.x + (1.0f - z0)*ht0;
  float hn1 = z1*hv.y + (1.0f - z1)*ht1;
  ((float2*)hl)[(size_t)d*64 + lane] = float2{hn0, hn1};
  if (has_out){
    if (fl){
      float* op = (float*)outbase + out_off;
      ((float2*)op)[(size_t)d*64 + lane] = float2{hn0, hn1};
    } else {
      unsigned short* op = (unsigned short*)outbase + out_off;
      ((unsigned int*)op)[(size_t)d*64 + lane] =
          (unsigned)f2bf(hn0) | ((unsigned)f2bf(hn1) << 16);
    }
  }
}

// ---------------- orchestration ----------------
extern "C" void kernel_launch(void* const* d_in, const int* in_sizes, int n_in,
                              void* d_out, int out_size, void* d_ws, size_t ws_size,
                              hipStream_t stream)
{
  const void* x  = d_in[0];
  const void* h0 = d_in[1];
  const int* ei  = (const int*)d_in[2];
  const void* Wm[6] = { d_in[3], d_in[4], d_in[5], d_in[6], d_in[7], d_in[8] };
  const void* bxz = d_in[9];
  const void* bhz = d_in[10];
  const void* bxr = d_in[11];
  const void* bhr = d_in[12];
  const void* bxh = d_in[13];
  const void* bhh = d_in[14];

  char* wp_ = (char*)d_ws;
  auto alloc = [&](size_t b)->char*{ char* p = wp_; wp_ += (b + 255) & ~(size_t)255; return p; };
  // small structures first
  int*   flag  = (int*)alloc(256);
  float* dinv  = (float*)alloc((size_t)NN*4);
  int*   counts= (int*)alloc((size_t)NN*4);
  int*   rowptr= (int*)alloc((size_t)(NN+1)*4);
  int*   cursor= (int*)alloc((size_t)NN*4);
  int*   part  = (int*)alloc(1024);
  int*   pscan = (int*)alloc(1024);
  int*   colss = (int*)alloc((size_t)EE*4);              // 3.2 MB
  float* wsrc  = (float*)alloc((size_t)EE*4);            // 3.2 MB
  unsigned short* Wt_hi = (unsigned short*)alloc((size_t)12*16384*2);
  unsigned short* Wt_lo = (unsigned short*)alloc((size_t)12*16384*2);
  // big buffers last
  float*   h     = (float*)alloc((size_t)LL*NN*HH*4);    // 51.2 MB
  float*   U     = (float*)alloc((size_t)NN*HH*4);       // 25.6 MB
  __half2* zbuf  = (__half2*)alloc((size_t)NN*HH*2);     // 12.8 MB
  __half2* rhbuf = (__half2*)alloc((size_t)NN*HH*2);     // 12.8 MB
  // total ~110.5 MB

  k_detect<<<1, 256, 0, stream>>>((const unsigned short*)x, flag);
  hipMemsetAsync(counts, 0, (size_t)NN*4, stream);
  hipMemsetAsync(colss, 0, (size_t)EE*4, stream);
  hipMemsetAsync(wsrc,  0, (size_t)EE*4, stream);
  k_hist<<<(EE+255)/256, 256, 0, stream>>>(ei, counts, EE);
  k_dinv<<<(NN+255)/256, 256, 0, stream>>>(counts, dinv, NN);
  k_reduce<<<196, 256, 0, stream>>>(counts, part, NN);
  k_scan_partials<<<1, 256, 0, stream>>>(part, pscan, 196, rowptr, NN, EE);
  k_scan_final<<<196, 256, 0, stream>>>(counts, pscan, rowptr, cursor, NN);
  k_fill<<<(EE+255)/256, 256, 0, stream>>>(ei, ei+EE, cursor, dinv, colss, wsrc, EE);
  k_h0<<<(LL*NN*HH+255)/256, 256, 0, stream>>>(h0, h, flag, LL*NN*HH);
  k_transpose<<<dim3(64,12), 256, 0, stream>>>(Wm[0],Wm[1],Wm[2],Wm[3],Wm[4],Wm[5],
                                               Wt_hi, Wt_lo, flag);

  const int gx = (NN + 127) / 128;   // 391
  const int pg = NN / 4;             // 12500
  for (int t=0; t<TT; ++t){
    for (int l=0; l<LL; ++l){
      const void* S1 = (l==0) ? x : (const void*)h;   // layer1 input = updated h[0] (f32)
      long s1_off = (l==0) ? (long)t*NN*HH : 0;
      int s1_is_x = (l==0) ? 1 : 0;
      float* hl = h + (size_t)l*NN*HH;
      // z gate
      gemm_one<<<gx, 256, 0, stream>>>(S1, s1_off, s1_is_x, hl, 0,
          Wt_hi + (0*2+l)*16384, Wt_hi + (1*2+l)*16384,
          Wt_lo + (0*2+l)*16384, Wt_lo + (1*2+l)*16384, U, NN, flag);
      prop_sig<<<pg, 256, 0, stream>>>(U, rowptr, colss, wsrc, dinv,
          bxz, bhz, l*HH, hl, zbuf, 0, flag, NN);
      // r gate -> r*h (fp16)
      gemm_one<<<gx, 256, 0, stream>>>(S1, s1_off, s1_is_x, hl, 0,
          Wt_hi + (2*2+l)*16384, Wt_hi + (3*2+l)*16384,
          Wt_lo + (2*2+l)*16384, Wt_lo + (3*2+l)*16384, U, NN, flag);
      prop_sig<<<pg, 256, 0, stream>>>(U, rowptr, colss, wsrc, dinv,
          bxr, bhr, l*HH, hl, rhbuf, 1, flag, NN);
      // candidate + state update
      gemm_one<<<gx, 256, 0, stream>>>(S1, s1_off, s1_is_x, rhbuf, 1,
          Wt_hi + (4*2+l)*16384, Wt_hi + (5*2+l)*16384,
          Wt_lo + (4*2+l)*16384, Wt_lo + (5*2+l)*16384, U, NN, flag);
      prop_h<<<pg, 256, 0, stream>>>(U, rowptr, colss, wsrc, dinv,
          bxh, bhh, l*HH, zbuf, hl,
          d_out, (long)t*NN*HH, (l==LL-1) ? 1 : 0, flag, NN);
    }
  }
}